// Round 6
// baseline (306.688 us; speedup 1.0000x reference)
//
#include <hip/hip_runtime.h>
#include <stdint.h>

#define THREADS 256
#define WAVE_DW 1792        // LDS dwords per wave: 64 samples x 28 dwords
#define GDW     28          // dwords per sample-group slot (27 data + 1 slack)

typedef const __attribute__((address_space(1))) uint32_t* gas_ptr;
typedef __attribute__((address_space(3))) uint32_t*       las_ptr;

__device__ __forceinline__ float fast_sigmoid(float v) {
    float e = __expf(-v);
    return __builtin_amdgcn_rcpf(1.0f + e);
}

// R5 post-mortem: occupancy 18->40% left VALUBusy pinned at 40% -> issue is
// capped by something occupancy-independent. Theory: (1) ~18KB of fully
// unrolled straight-line code streams through I$ every iteration; (2) waves
// convoy on the per-group vmcnt(0) drain (identical phase lengths).
//
// R6: roll the G-loop (code ~3x smaller, I$-resident; group math identical
// modulo uniform scalar weight bases) and rotate group order per wave
// (Ga = (G+wid)%3) so the 4 waves of a block stage at different times.
// Staging/layout/repair byte-identical to the passing R5 kernel.
__global__ __launch_bounds__(THREADS, 4) void olcnn_kernel(
    const float* __restrict__ x,
    const float* __restrict__ Wc, const float* __restrict__ bc,
    const float* __restrict__ Wh, const float* __restrict__ bh,
    const float* __restrict__ Wm, const float* __restrict__ bm,
    const float* __restrict__ Wo, const float* __restrict__ bo,
    float* __restrict__ out)
{
    __shared__ __align__(16) float sm[4 * WAVE_DW];   // 28672 B -> 5 blk/CU

    const int tid   = threadIdx.x;
    const int lane  = tid & 63;
    const int wid   = tid >> 6;
    const int samp  = blockIdx.x * THREADS + tid;
    const int TOTAL = (int)gridDim.x * THREADS * 81;  // dwords in x
    const int LIM   = TOTAL - 4;
    const int LAST  = (int)gridDim.x * THREADS - 1;

    float* smw = sm + wid * WAVE_DW;                  // wave-private slice
    const int wbase81 = (blockIdx.x * THREADS + wid * 64) * 81;

    // per-lane staging decomposition (invariant across groups)
    const int t0 = (lane * 9363) >> 16;               // lane / 7 (exact)
    const int r0 = lane - t0 * 7;

    float res0 = 0.f, res1 = 0.f, res2 = 0.f, res3 = 0.f;

    #pragma unroll 1
    for (int G = 0; G < 3; ++G) {
        int Ga = G + wid;                             // wave-rotated group
        Ga = (Ga >= 3) ? Ga - 3 : Ga;                 // values <=5 -> one sub

        // WAR fence: prior group's ds_reads retire before DMA overwrites.
        asm volatile("s_waitcnt lgkmcnt(0)" ::: "memory");
        __builtin_amdgcn_sched_barrier(0);

        // ---- stage group Ga for this wave's 64 samples (7x 16B/lane) ----
        {
            int t81 = t0 * 81;
            int r   = r0;
            const int gofs = wbase81 + Ga * 27;
            #pragma unroll
            for (int i = 0; i < 7; ++i) {
                int f0 = gofs + t81 + (r << 2);
                f0 = (f0 < LIM) ? f0 : LIM;           // clamps one chunk globally
                __builtin_amdgcn_global_load_lds(
                    (gas_ptr)(x + f0), (las_ptr)(smw + i * 256), 16, 0, 0);
                t81 += (r == 6) ? 810 : 729;          // chunk += 64
                r = (r == 6) ? 0 : r + 1;
            }
        }
        asm volatile("s_waitcnt vmcnt(0)" ::: "memory");  // DMA visible

        // ---- own sample's 27 inputs (2-way bank pattern: free) ----
        float p[28];
        {
            const float4* rp = (const float4*)(smw + lane * GDW);
            #pragma unroll
            for (int q = 0; q < 7; ++q) {
                float4 v = rp[q];
                p[4*q+0] = v.x; p[4*q+1] = v.y; p[4*q+2] = v.z; p[4*q+3] = v.w;
            }
        }
        if (samp == LAST && Ga == 2) {                // repair clamped chunk
            p[24] = x[TOTAL - 3]; p[25] = x[TOTAL - 2]; p[26] = x[TOTAL - 1];
        }

        // uniform (scalar) weight bases for group Ga
        const float* wcP = Wc + Ga * 243;
        const float* bcP = bc + Ga * 27;
        const float* whP = Wh + Ga * 81;
        const float* bhP = bh + Ga * 9;
        const float* wmP = Wm + Ga * 36;
        const float* bmP = bm + Ga * 4;

        float hb[9];
        #pragma unroll
        for (int j = 0; j < 3; ++j) {                 // compile-time j
            float feat[9];
            #pragma unroll
            for (int k = 0; k < 9; ++k) {             // 9 independent chains
                float acc = bcP[j * 9 + k];
                #pragma unroll
                for (int pr = 0; pr < 3; ++pr)
                    #pragma unroll
                    for (int pc = 0; pc < 3; ++pc)
                        acc = fmaf(p[pr * 9 + j * 3 + pc],
                                   wcP[j * 81 + k * 9 + pr * 3 + pc], acc);
                feat[k] = fast_sigmoid(acc);
            }
            #pragma unroll
            for (int n = 0; n < 3; ++n) {
                float acc = bhP[j * 3 + n];
                #pragma unroll
                for (int pi = 0; pi < 9; ++pi)
                    acc = fmaf(feat[pi], whP[j * 27 + n * 9 + pi], acc);
                hb[j * 3 + n] = fast_sigmoid(acc);
            }
        }

        float m[4];
        #pragma unroll
        for (int n = 0; n < 4; ++n) {
            float acc = bmP[n];
            #pragma unroll
            for (int pi = 0; pi < 9; ++pi)
                acc = fmaf(hb[pi], wmP[n * 9 + pi], acc);
            m[n] = fast_sigmoid(acc);
        }

        // class c = Ga, plus class 3 on the Ga==0 iteration (uniform branch)
        float accA = bo[Ga];
        #pragma unroll
        for (int pi = 0; pi < 4; ++pi)
            accA = fmaf(m[pi], Wo[Ga * 4 + pi], accA);

        if (Ga == 0) {
            float accB = bo[3];
            #pragma unroll
            for (int pi = 0; pi < 4; ++pi)
                accB = fmaf(m[pi], Wo[12 + pi], accB);
            res0 = accA; res3 = accB;
        } else if (Ga == 1) {
            res1 = accA;
        } else {
            res2 = accA;
        }
    }

    float4 o;
    o.x = res0; o.y = res1; o.z = res2; o.w = res3;
    ((float4*)out)[samp] = o;                          // coalesced 16B store
}

extern "C" void kernel_launch(void* const* d_in, const int* in_sizes, int n_in,
                              void* d_out, int out_size, void* d_ws, size_t ws_size,
                              hipStream_t stream) {
    const float* x  = (const float*)d_in[0];
    const float* Wc = (const float*)d_in[1];
    const float* bc = (const float*)d_in[2];
    const float* Wh = (const float*)d_in[3];
    const float* bh = (const float*)d_in[4];
    const float* Wm = (const float*)d_in[5];
    const float* bm = (const float*)d_in[6];
    const float* Wo = (const float*)d_in[7];
    const float* bo = (const float*)d_in[8];
    float* out = (float*)d_out;

    const int B = in_sizes[0] / 81;                // 524288
    const int blocks = B / THREADS;                // 2048
    olcnn_kernel<<<blocks, THREADS, 0, stream>>>(x, Wc, bc, Wh, bh, Wm, bm,
                                                 Wo, bo, out);
}

// Round 7
// 292.081 us; speedup vs baseline: 1.0500x; 1.0500x over previous
//
#include <hip/hip_runtime.h>
#include <stdint.h>

#define THREADS 64          // 1 wave per block: self-pipelined, no convoy
#define BUF_DW  1792        // 64 samples x 28 dwords per group-buffer

typedef const __attribute__((address_space(1))) uint32_t* gas_ptr;
typedef __attribute__((address_space(3))) uint32_t*       las_ptr;

__device__ __forceinline__ float fast_sigmoid(float v) {
    float e = __expf(-v);
    return __builtin_amdgcn_rcpf(1.0f + e);
}

// Group-G compute, compile-time G (constant weight offsets -> s_load hoisting).
template<int G>
__device__ __forceinline__ void compute_group(
    const float* __restrict__ p,
    const float* __restrict__ Wc, const float* __restrict__ bc,
    const float* __restrict__ Wh, const float* __restrict__ bh,
    const float* __restrict__ Wm, const float* __restrict__ bm,
    const float* __restrict__ Wo, const float* __restrict__ bo,
    float& outA, float& outB)
{
    float hb[9];
    #pragma unroll
    for (int j = 0; j < 3; ++j) {
        const int g = G * 3 + j;
        float feat[9];
        #pragma unroll
        for (int k = 0; k < 9; ++k) {              // 9 independent chains
            float acc = bc[g * 9 + k];
            #pragma unroll
            for (int pr = 0; pr < 3; ++pr)
                #pragma unroll
                for (int pc = 0; pc < 3; ++pc)
                    acc = fmaf(p[pr * 9 + j * 3 + pc],
                               Wc[(g * 9 + k) * 9 + pr * 3 + pc], acc);
            feat[k] = fast_sigmoid(acc);
        }
        #pragma unroll
        for (int n = 0; n < 3; ++n) {
            float acc = bh[g * 3 + n];
            #pragma unroll
            for (int pi = 0; pi < 9; ++pi)
                acc = fmaf(feat[pi], Wh[(g * 3 + n) * 9 + pi], acc);
            hb[j * 3 + n] = fast_sigmoid(acc);
        }
    }
    float m[4];
    #pragma unroll
    for (int n = 0; n < 4; ++n) {
        float acc = bm[G * 4 + n];
        #pragma unroll
        for (int pi = 0; pi < 9; ++pi)
            acc = fmaf(hb[pi], Wm[(G * 4 + n) * 9 + pi], acc);
        m[n] = fast_sigmoid(acc);
    }
    float acc = bo[G];
    #pragma unroll
    for (int pi = 0; pi < 4; ++pi)
        acc = fmaf(m[pi], Wo[G * 4 + pi], acc);
    outA = acc;
    if (G == 0) {                                   // class 3 reads group 0
        float acc2 = bo[3];
        #pragma unroll
        for (int pi = 0; pi < 4; ++pi)
            acc2 = fmaf(m[pi], Wo[12 + pi], acc2);
        outB = acc2;
    }
}

// R6 post-mortem: occupancy-independent 40->21% VALUBusy at same 126us ->
// every wave's serial stage->vmcnt(0)->compute chain convoys; the ~900cy
// HBM drain sits on every critical path. R7: double-buffered issue-early/
// wait-late staging with COUNTED vmcnt (never 0 until the last buffer):
// only the initial drain is exposed (~10% of wave life). 1-wave blocks,
// 14336B LDS -> 11 blocks/CU.
__global__ __launch_bounds__(THREADS, 4) void olcnn_kernel(
    const float* __restrict__ x,
    const float* __restrict__ Wc, const float* __restrict__ bc,
    const float* __restrict__ Wh, const float* __restrict__ bh,
    const float* __restrict__ Wm, const float* __restrict__ bm,
    const float* __restrict__ Wo, const float* __restrict__ bo,
    float* __restrict__ out)
{
    __shared__ __align__(16) float sm[2 * BUF_DW];   // 14336 B

    const int lane  = threadIdx.x;
    const int samp  = blockIdx.x * THREADS + lane;
    const int TOTAL = (int)gridDim.x * THREADS * 81; // dwords in x
    const int LIM   = TOTAL - 4;
    const int LAST  = (int)gridDim.x * THREADS - 1;
    const int wbase81 = blockIdx.x * THREADS * 81;

    const int t0 = (lane * 9363) >> 16;              // lane / 7 (exact, <64)
    const int r0 = lane - t0 * 7;

    // stage group Ga into LDS buffer dst (7 x 16B per lane, coalesced)
    auto STAGE = [&](int Ga, float* dst) {
        int t81 = t0 * 81;
        int r   = r0;
        const int gofs = wbase81 + Ga * 27;
        #pragma unroll
        for (int i = 0; i < 7; ++i) {
            int f0 = gofs + t81 + (r << 2);
            f0 = (f0 < LIM) ? f0 : LIM;              // clamps one chunk globally
            __builtin_amdgcn_global_load_lds(
                (gas_ptr)(x + f0), (las_ptr)(dst + i * 256), 16, 0, 0);
            t81 += (r == 6) ? 810 : 729;             // chunk += 64
            r = (r == 6) ? 0 : r + 1;
        }
    };
    auto READP = [&](const float* buf, float* p) {   // own sample's 28 dwords
        const float4* rp = (const float4*)(buf + lane * 28);
        #pragma unroll
        for (int q = 0; q < 7; ++q) {
            float4 v = rp[q];
            p[4*q+0] = v.x; p[4*q+1] = v.y; p[4*q+2] = v.z; p[4*q+3] = v.w;
        }
    };

    float res0, res1, res2, res3;

    STAGE(0, sm);                                    // 7 vm ops
    STAGE(1, sm + BUF_DW);                           // 7 more (14 in flight)

    asm volatile("s_waitcnt vmcnt(7)" ::: "memory"); // buf0 ready (only real drain)
    float p0[28];
    READP(sm, p0);
    asm volatile("s_waitcnt lgkmcnt(0)" ::: "memory"); // buf0 reads retired (WAR)
    STAGE(2, sm);                                    // overwrite buf0; covered by
                                                     // compute(0)+compute(1)
    compute_group<0>(p0, Wc, bc, Wh, bh, Wm, bm, Wo, bo, res0, res3);

    asm volatile("s_waitcnt vmcnt(7)" ::: "memory"); // buf1 ready (~0 wait)
    float p1[28];
    READP(sm + BUF_DW, p1);                          // compiler inserts lgkm waits
    compute_group<1>(p1, Wc, bc, Wh, bh, Wm, bm, Wo, bo, res1, res1);

    asm volatile("s_waitcnt vmcnt(0)" ::: "memory"); // buf0(stage2) ready (~0)
    float p2[28];
    READP(sm, p2);
    if (samp == LAST) {                              // repair the clamped chunk
        p2[24] = x[TOTAL - 3]; p2[25] = x[TOTAL - 2]; p2[26] = x[TOTAL - 1];
    }
    compute_group<2>(p2, Wc, bc, Wh, bh, Wm, bm, Wo, bo, res2, res2);

    float4 o;
    o.x = res0; o.y = res1; o.z = res2; o.w = res3;
    ((float4*)out)[samp] = o;                        // coalesced 16B store
}

extern "C" void kernel_launch(void* const* d_in, const int* in_sizes, int n_in,
                              void* d_out, int out_size, void* d_ws, size_t ws_size,
                              hipStream_t stream) {
    const float* x  = (const float*)d_in[0];
    const float* Wc = (const float*)d_in[1];
    const float* bc = (const float*)d_in[2];
    const float* Wh = (const float*)d_in[3];
    const float* bh = (const float*)d_in[4];
    const float* Wm = (const float*)d_in[5];
    const float* bm = (const float*)d_in[6];
    const float* Wo = (const float*)d_in[7];
    const float* bo = (const float*)d_in[8];
    float* out = (float*)d_out;

    const int B = in_sizes[0] / 81;                // 524288
    const int blocks = B / THREADS;                // 8192 one-wave blocks
    olcnn_kernel<<<blocks, THREADS, 0, stream>>>(x, Wc, bc, Wh, bh, Wm, bm,
                                                 Wo, bo, out);
}